// Round 10
// baseline (1781.536 us; speedup 1.0000x reference)
//
#include <hip/hip_runtime.h>
#include <math.h>

namespace {

constexpr int TSEQ   = 2048;
constexpr int DIN    = 16;
constexpr int NH1    = 5;
constexpr int NH2    = 50;
constexpr int NCLS   = 20;
constexpr int CHUNK  = 64;
constexpr int NCHUNK = TSEQ / CHUNK;
constexpr int BATCH  = 256;
constexpr int GXS    = 21;   // gx row stride (odd -> conflict-free)

typedef float v2f __attribute__((ext_vector_type(2)));

// No clamp: exp(+inf)->inf, rcp(inf)->0 — still correct; inputs bounded.
__device__ __forceinline__ float fast_sigm(float x) {
    return __fdividef(1.f, 1.f + __expf(-x));
}
// tanh(x) = 2*sigm(2x) - 1
__device__ __forceinline__ float fast_tanh(float x) {
    return fmaf(2.f, fast_sigm(2.f * x), -1.f);
}

// quad_perm DPP: VALU-speed cross-lane within aligned quads.
template <int CTRL>
__device__ __forceinline__ float qperm(float v) {
    int i = __builtin_bit_cast(int, v);
    int r = __builtin_amdgcn_update_dpp(i, i, CTRL, 0xf, 0xf, false);
    return __builtin_bit_cast(float, r);
}
__device__ __forceinline__ float rdlane(float v, int lane) {
    return __builtin_bit_cast(float,
        __builtin_amdgcn_readlane(__builtin_bit_cast(int, v), lane));
}

struct L1State {
    float c1;
    float h0, h1, h2, h3, h4;   // wave-uniform -> SGPRs
};

// One L1 timestep. Lane 4j+g owns row r=g*5+j (j<5). Lanes >=20 compute
// garbage harmlessly (readlane only pulls lanes 0..16).
__device__ __forceinline__ void l1_step(float gx, float bias1,
                                        const float* __restrict__ w1h,
                                        float isc1, float osc1, float off1,
                                        L1State& st) {
    float g1 = gx + bias1;
    g1 = fmaf(st.h0, w1h[0], g1);
    g1 = fmaf(st.h1, w1h[1], g1);
    g1 = fmaf(st.h2, w1h[2], g1);
    g1 = fmaf(st.h3, w1h[3], g1);
    g1 = fmaf(st.h4, w1h[4], g1);
    float act = fmaf(osc1, fast_sigm(isc1 * g1), off1);
    float f_ = qperm<0xB1>(act);
    float gg = qperm<0x4E>(act);
    float o_ = qperm<0x1B>(act);
    st.c1 = fmaf(f_, st.c1, act * gg);          // valid on lanes 4j+0
    float h1me = o_ * fast_tanh(st.c1);
    st.h0 = rdlane(h1me, 0);
    st.h1 = rdlane(h1me, 4);
    st.h2 = rdlane(h1me, 8);
    st.h3 = rdlane(h1me, 12);
    st.h4 = rdlane(h1me, 16);
}

// ONE WAVE per batch element; grid 256 x 64 threads. Lane u (<50) owns ALL
// 4 gates of L2 unit u (100 v2f weight pairs in VGPRs). Gates never leave
// the lane; h2 crosses lanes via same-wave LDS (1 write + 13 broadcast
// b128 reads, in-order, ZERO barriers in the whole kernel).
__global__ __launch_bounds__(64, 1) void lstm_fused_kernel(
    const float* __restrict__ x,     // (256,2048,16)
    const float* __restrict__ W1ih,  // (20,16)
    const float* __restrict__ W1hh,  // (20,5)
    const float* __restrict__ b1ih,  // (20)
    const float* __restrict__ b1hh,  // (20)
    const float* __restrict__ W2ih,  // (200,5)
    const float* __restrict__ W2hh,  // (200,50)
    const float* __restrict__ b2ih,  // (200)
    const float* __restrict__ b2hh,  // (200)
    const float* __restrict__ Wfc,   // (20,50)
    const float* __restrict__ bfc,   // (20)
    float* __restrict__ out)         // result(256,20) ++ last(256,50)
{
    const int b    = blockIdx.x;
    const int lane = threadIdx.x;    // 0..63, single wave

    __shared__ float s_w1[NCLS * DIN];           // 320
    __shared__ float s_gx[(CHUNK + 1) * GXS];    // x-part gates (+pad row)
    __shared__ __align__(16) float s_h2[2][64];  // h2 double buffer

    for (int i = lane; i < NCLS * DIN; i += 64) s_w1[i] = W1ih[i];
    s_h2[0][lane] = 0.f;
    s_h2[1][lane] = 0.f;

    // ---- layer-1: lane 4j+g owns row r = g*5+j (lanes 0..19) ----
    const int r1 = (lane < NCLS) ? ((lane & 3) * NH1 + (lane >> 2)) : 0;
    float w1h[NH1];
    #pragma unroll
    for (int j = 0; j < NH1; ++j) w1h[j] = W1hh[r1 * NH1 + j];
    const float bias1 = b1ih[r1] + b1hh[r1];
    const bool  isg1  = ((lane & 3) == 2) && (lane < NCLS);
    const float isc1  = isg1 ? 2.f : 1.f;
    const float osc1  = isg1 ? 2.f : 1.f;
    const float off1  = isg1 ? -1.f : 0.f;

    // ---- layer-2: lane u owns unit u, all 4 gates, full K=50 ----
    const int u    = (lane < NH2) ? lane : 0;
    const bool on2 = (lane < NH2);

    v2f   wg[4][25];     // 200 floats of W2hh
    float w2i[4][NH1];   // 20 floats of W2ih
    float b2[4];
    #pragma unroll
    for (int gi = 0; gi < 4; ++gi) {
        const int rr = gi * NH2 + u;
        const float2* wr = (const float2*)(W2hh + rr * NH2);   // 200B rows, 8B ok
        #pragma unroll
        for (int j = 0; j < 25; ++j) {
            float2 v = wr[j];
            wg[gi][j] = v2f{v.x, v.y};
        }
        #pragma unroll
        for (int d = 0; d < NH1; ++d) w2i[gi][d] = W2ih[rr * NH1 + d];
        b2[gi] = b2ih[rr] + b2hh[rr];
    }

    L1State st = {0.f, 0.f, 0.f, 0.f, 0.f, 0.f};
    float c2 = 0.f, hlast = 0.f;

    // x: lane = step-in-chunk; 16 floats = 4 float4, refilled each chunk
    const float* xb = x + (size_t)b * TSEQ * DIN;
    float4 xr[4];
    #pragma unroll
    for (int i = 0; i < 4; ++i)
        xr[i] = ((const float4*)(xb + (size_t)lane * DIN))[i];

    // ---- one timestep; SRC/DST compile-time parity; zero barriers ----
    #define LSTM_STEP(SRC, DST, TT, DO_L1)                                     \
    {                                                                          \
        float4 hr[13];                                                         \
        {                                                                      \
            const float4* hb = (const float4*)s_h2[SRC];   /* broadcast */     \
            _Pragma("unroll")                                                  \
            for (int j = 0; j < 13; ++j) hr[j] = hb[j];                        \
        }                                                                      \
        const v2f* hp = (const v2f*)hr;                                        \
        float gxn = s_gx[(TT + 1) * GXS + r1];                                 \
        /* ih part + bias while LDS reads are in flight */                     \
        float ih0 = b2[0], ih1 = b2[1], ih2 = b2[2], ih3 = b2[3];              \
        _Pragma("unroll")                                                      \
        for (int d = 0; d < NH1; ++d) {                                        \
            const float hv = (d == 0) ? st.h0 : (d == 1) ? st.h1               \
                             : (d == 2) ? st.h2 : (d == 3) ? st.h3 : st.h4;    \
            ih0 = fmaf(hv, w2i[0][d], ih0);                                    \
            ih1 = fmaf(hv, w2i[1][d], ih1);                                    \
            ih2 = fmaf(hv, w2i[2][d], ih2);                                    \
            ih3 = fmaf(hv, w2i[3][d], ih3);                                    \
        }                                                                      \
        v2f aA0 = v2f{ih0, 0.f}, aA1 = v2f{ih1, 0.f};                          \
        v2f aA2 = v2f{ih2, 0.f}, aA3 = v2f{ih3, 0.f};                          \
        v2f aB0 = v2f{0.f, 0.f}, aB1 = v2f{0.f, 0.f};                          \
        v2f aB2 = v2f{0.f, 0.f}, aB3 = v2f{0.f, 0.f};                          \
        /* 100 v_pk_fma_f32, 8 independent chains */                           \
        _Pragma("unroll")                                                      \
        for (int j = 0; j < 25; j += 2) {                                      \
            aA0 = __builtin_elementwise_fma(hp[j], wg[0][j], aA0);             \
            aA1 = __builtin_elementwise_fma(hp[j], wg[1][j], aA1);             \
            aA2 = __builtin_elementwise_fma(hp[j], wg[2][j], aA2);             \
            aA3 = __builtin_elementwise_fma(hp[j], wg[3][j], aA3);             \
            if (j + 1 < 25) {                                                  \
                aB0 = __builtin_elementwise_fma(hp[j+1], wg[0][j+1], aB0);     \
                aB1 = __builtin_elementwise_fma(hp[j+1], wg[1][j+1], aB1);     \
                aB2 = __builtin_elementwise_fma(hp[j+1], wg[2][j+1], aB2);     \
                aB3 = __builtin_elementwise_fma(hp[j+1], wg[3][j+1], aB3);     \
            }                                                                  \
        }                                                                      \
        /* L1 for step t+1 (independent; overlaps activation latency) */       \
        if (DO_L1)                                                             \
            l1_step(gxn, bias1, w1h, isc1, osc1, off1, st);                    \
        v2f g0 = aA0 + aB0, g1 = aA1 + aB1;                                    \
        v2f g2 = aA2 + aB2, g3 = aA3 + aB3;                                    \
        float pi = g0.x + g0.y;                                                \
        float pf = g1.x + g1.y;                                                \
        float pg = g2.x + g2.y;                                                \
        float po = g3.x + g3.y;                                                \
        float i2 = fast_sigm(pi);                                              \
        float f2 = fast_sigm(pf);                                              \
        float gg2 = fast_tanh(pg);                                             \
        float o2 = fast_sigm(po);                                              \
        c2 = fmaf(f2, c2, i2 * gg2);                                           \
        hlast = o2 * fast_tanh(c2);                                            \
        if (on2) s_h2[DST][lane] = hlast;     /* 1 ds_write_b32 */             \
    }

    #pragma unroll 1
    for (int c = 0; c < NCHUNK; ++c) {
        // ---- gx phase: lane = step; 20 rows x 16-dot from broadcast W1 ----
        {
            const float* xf = (const float*)xr;
            #pragma unroll 4
            for (int rw = 0; rw < NCLS; ++rw) {
                const float4* wv4 = (const float4*)(s_w1 + rw * DIN);
                float4 w0 = wv4[0], w1 = wv4[1], w2_ = wv4[2], w3 = wv4[3];
                float s = w0.x * xf[0];
                s = fmaf(w0.y, xf[1], s);  s = fmaf(w0.z, xf[2], s);  s = fmaf(w0.w, xf[3], s);
                s = fmaf(w1.x, xf[4], s);  s = fmaf(w1.y, xf[5], s);  s = fmaf(w1.z, xf[6], s);
                s = fmaf(w1.w, xf[7], s);  s = fmaf(w2_.x, xf[8], s); s = fmaf(w2_.y, xf[9], s);
                s = fmaf(w2_.z, xf[10], s); s = fmaf(w2_.w, xf[11], s); s = fmaf(w3.x, xf[12], s);
                s = fmaf(w3.y, xf[13], s); s = fmaf(w3.z, xf[14], s); s = fmaf(w3.w, xf[15], s);
                s_gx[lane * GXS + rw] = s;   // stride 21 -> conflict-free
            }
        }
        // refill xr for next chunk; stays in flight across the step loop
        {
            const int cn = (c + 1 < NCHUNK) ? c + 1 : c;
            const float4* xs = (const float4*)(xb + ((size_t)cn * CHUNK + lane) * DIN);
            #pragma unroll
            for (int i = 0; i < 4; ++i) xr[i] = xs[i];
        }
        __builtin_amdgcn_wave_barrier();   // compiler fence (in-order wave)

        // chunk preamble: L1 for this chunk's step 0
        l1_step(s_gx[r1], bias1, w1h, isc1, osc1, off1, st);

        #pragma unroll 1
        for (int tt = 0; tt < CHUNK; tt += 2) {
            LSTM_STEP(0, 1, tt, true)
            LSTM_STEP(1, 0, tt + 1, (tt < CHUNK - 2))
        }
    }
    #undef LSTM_STEP

    // final h2: per-lane hlast (lane<50) and s_h2[0] (even #steps/chunk)
    // ---- outputs: result(256,20) @0, last(256,50) @5120 ----
    if (lane < NH2) out[BATCH * NCLS + b * NH2 + lane] = hlast;
    if (lane < NCLS) {
        float acc = bfc[lane];
        const float* wr = Wfc + lane * NH2;
        #pragma unroll
        for (int j = 0; j < NH2; ++j) acc = fmaf(s_h2[0][j], wr[j], acc);
        out[b * NCLS + lane] = acc;
    }
}

} // namespace

extern "C" void kernel_launch(void* const* d_in, const int* in_sizes, int n_in,
                              void* d_out, int out_size, void* d_ws, size_t ws_size,
                              hipStream_t stream) {
    (void)in_sizes; (void)n_in; (void)d_ws; (void)ws_size; (void)out_size;
    const float* x    = (const float*)d_in[0];
    const float* W1ih = (const float*)d_in[1];
    const float* W1hh = (const float*)d_in[2];
    const float* b1ih = (const float*)d_in[3];
    const float* b1hh = (const float*)d_in[4];
    const float* W2ih = (const float*)d_in[5];
    const float* W2hh = (const float*)d_in[6];
    const float* b2ih = (const float*)d_in[7];
    const float* b2hh = (const float*)d_in[8];
    const float* Wfc  = (const float*)d_in[9];
    const float* bfc  = (const float*)d_in[10];

    lstm_fused_kernel<<<dim3(BATCH), dim3(64), 0, stream>>>(
        x, W1ih, W1hh, b1ih, b1hh, W2ih, W2hh, b2ih, b2hh, Wfc, bfc,
        (float*)d_out);
}

// Round 11
// 1017.315 us; speedup vs baseline: 1.7512x; 1.7512x over previous
//
#include <hip/hip_runtime.h>
#include <math.h>

namespace {

constexpr int TSEQ   = 2048;
constexpr int DIN    = 16;
constexpr int NH1    = 5;
constexpr int NH2    = 50;
constexpr int NCLS   = 20;
constexpr int CHUNK  = 64;
constexpr int NCHUNK = TSEQ / CHUNK;
constexpr int BATCH  = 256;
constexpr int GXS    = 21;   // gx row stride (odd -> conflict-free)
constexpr int XS     = 17;   // s_x row stride (odd -> conflict-free)
constexpr int KW     = 15;   // max K-slice width (w0/w1=15, w2=14, w3=12)

// No clamp: exp(+inf)->inf, rcp(inf)->0 — still correct; inputs bounded.
__device__ __forceinline__ float fast_sigm(float x) {
    return __fdividef(1.f, 1.f + __expf(-x));
}
// tanh(x) = 2*sigm(2x) - 1
__device__ __forceinline__ float fast_tanh(float x) {
    return fmaf(2.f, fast_sigm(2.f * x), -1.f);
}

// quad_perm DPP: VALU-speed cross-lane within aligned quads.
template <int CTRL>
__device__ __forceinline__ float qperm(float v) {
    int i = __builtin_bit_cast(int, v);
    int r = __builtin_amdgcn_update_dpp(i, i, CTRL, 0xf, 0xf, false);
    return __builtin_bit_cast(float, r);
}
__device__ __forceinline__ float rdlane(float v, int lane) {
    return __builtin_bit_cast(float,
        __builtin_amdgcn_readlane(__builtin_bit_cast(int, v), lane));
}

struct L1State {
    float c1;
    float h0, h1, h2, h3, h4;   // wave-uniform -> SGPRs
};

// One L1 timestep. Lane 4j+g owns row r=g*5+j (j<5).
__device__ __forceinline__ void l1_step(float gx, float bias1,
                                        const float* __restrict__ w1h,
                                        float isc1, float osc1, float off1,
                                        L1State& st) {
    float g1 = gx + bias1;
    g1 = fmaf(st.h0, w1h[0], g1);
    g1 = fmaf(st.h1, w1h[1], g1);
    g1 = fmaf(st.h2, w1h[2], g1);
    g1 = fmaf(st.h3, w1h[3], g1);
    g1 = fmaf(st.h4, w1h[4], g1);
    float act = fmaf(osc1, fast_sigm(isc1 * g1), off1);
    float f_ = qperm<0xB1>(act);
    float gg = qperm<0x4E>(act);
    float o_ = qperm<0x1B>(act);
    st.c1 = fmaf(f_, st.c1, act * gg);          // valid on lanes 4j+0
    float h1me = o_ * fast_tanh(st.c1);
    st.h0 = rdlane(h1me, 0);
    st.h1 = rdlane(h1me, 4);
    st.h2 = rdlane(h1me, 8);
    st.h3 = rdlane(h1me, 12);
    st.h4 = rdlane(h1me, 16);
}

// One block = 4 waves = one batch element. Split-K over an AUGMENTED K:
// columns = [h2(50) | h1(5) | bias(1)]. Slices: w0=h2[0..14], w1=h2[15..29],
// w2=h2[30..43], w3=h2[44..49]+h1+bias. Partial lane = unit (4 gates as one
// contiguous float4 -> conflict-free); combine lane reads 4*u+g (consecutive
// lanes -> consecutive dwords, conflict-free). Post-barrier combine is a
// pure 4-way sum -> activation. L1 runs ONLY on wave 3 (sole h1 consumer).
__global__ __launch_bounds__(256, 1) void lstm_fused_kernel(
    const float* __restrict__ x,     // (256,2048,16)
    const float* __restrict__ W1ih,  // (20,16)
    const float* __restrict__ W1hh,  // (20,5)
    const float* __restrict__ b1ih,  // (20)
    const float* __restrict__ b1hh,  // (20)
    const float* __restrict__ W2ih,  // (200,5)
    const float* __restrict__ W2hh,  // (200,50)
    const float* __restrict__ b2ih,  // (200)
    const float* __restrict__ b2hh,  // (200)
    const float* __restrict__ Wfc,   // (20,50)
    const float* __restrict__ bfc,   // (20)
    float* __restrict__ out)         // result(256,20) ++ last(256,50)
{
    const int b    = blockIdx.x;
    const int tid  = threadIdx.x;
    const int lane = tid & 63;
    const int wv   = tid >> 6;

    __shared__ float s_w1[NCLS * DIN];                 // 320
    __shared__ __align__(16) float s_x[CHUNK * XS];    // padded x stage
    __shared__ float s_gx[(CHUNK + 1) * GXS];          // x-part gates (+pad)
    __shared__ __align__(16) float s_part[2][4][256];  // [buf][wave][4*u+g]
    __shared__ float s_h2[64];                         // final h2 mirror

    for (int i = tid; i < NCLS * DIN; i += 256) s_w1[i] = W1ih[i];
    if (tid < 64) s_h2[tid] = 0.f;

    // ---- layer-1 setup (used only by wave 3; cheap to load everywhere) ----
    const int r1 = (lane < NCLS) ? ((lane & 3) * NH1 + (lane >> 2)) : 0;
    float w1h[NH1];
    #pragma unroll
    for (int j = 0; j < NH1; ++j) w1h[j] = W1hh[r1 * NH1 + j];
    const float bias1 = b1ih[r1] + b1hh[r1];
    const bool  isg1  = ((lane & 3) == 2) && (lane < NCLS);
    const float isc1  = isg1 ? 2.f : 1.f;
    const float osc1  = isg1 ? 2.f : 1.f;
    const float off1  = isg1 ? -1.f : 0.f;

    // ---- per-wave K-slice geometry ----
    const int k0 = (wv == 0) ? 0 : (wv == 1) ? 15 : (wv == 2) ? 30 : 44;
    const int kw = (wv <  2) ? 15 : (wv == 2) ? 14 : 12;   // 12 = 6 h2 + 5 h1 + bias
    const int nu = (wv <  2) ? 15 : (wv == 2) ? 14 : 6;    // units owned (combine)

    // ---- partial weights: lane = unit; 4 gate rows over my K-slice ----
    float wp[4][KW];
    #pragma unroll
    for (int g = 0; g < 4; ++g) {
        const int row = g * NH2 + ((lane < NH2) ? lane : 0);
        #pragma unroll
        for (int kk = 0; kk < KW; ++kk) {
            float w = 0.f;
            if (lane < NH2 && kk < kw) {
                if (wv < 3)            w = W2hh[row * NH2 + k0 + kk];
                else if (kk < 6)       w = W2hh[row * NH2 + 44 + kk];
                else if (kk < 11)      w = W2ih[row * NH1 + (kk - 6)];
                else                   w = b2ih[row] + b2hh[row];   // kk == 11
            }
            wp[g][kk] = w;
        }
    }

    // ---- combine mapping: lane = 4*ul+g -> unit u = k0+ul ----
    const int ul   = lane >> 2;
    const int g    = lane & 3;
    const bool onc = (ul < nu);
    const int u    = k0 + (onc ? ul : 0);          // all owned u < 50
    const int crow = 4 * k0 + lane;                // = 4*u+g when onc; <256 always
    const bool  isg2 = (g == 2);
    const float isc2 = isg2 ? 2.f : 1.f;
    const float osc2 = isg2 ? 2.f : 1.f;
    const float off2 = isg2 ? -1.f : 0.f;

    float hsl[KW];                                 // wave-uniform multipliers
    #pragma unroll
    for (int k = 0; k < KW; ++k) hsl[k] = 0.f;
    if (wv == 3) hsl[11] = 1.f;                    // bias column

    L1State st = {0.f, 0.f, 0.f, 0.f, 0.f, 0.f};
    float c2 = 0.f;

    const float* xb = x + (size_t)b * TSEQ * DIN;
    __syncthreads();

    // ---- one timestep; BUF = compile-time parity ----
    #define LSTM_STEP(BUF, TT, DO_L1)                                          \
    {                                                                          \
        /* partial: 4 gate rows x KW augmented-K, h from SGPRs */              \
        float a0 = 0.f, a1 = 0.f, a2 = 0.f, a3 = 0.f;                          \
        _Pragma("unroll")                                                      \
        for (int kk = 0; kk < KW; ++kk) {                                      \
            a0 = fmaf(hsl[kk], wp[0][kk], a0);                                 \
            a1 = fmaf(hsl[kk], wp[1][kk], a1);                                 \
            a2 = fmaf(hsl[kk], wp[2][kk], a2);                                 \
            a3 = fmaf(hsl[kk], wp[3][kk], a3);                                 \
        }                                                                      \
        ((float4*)(&s_part[BUF][wv][0]))[lane] = make_float4(a0, a1, a2, a3);  \
        float gxn = 0.f;                                                       \
        if (wv == 3) gxn = s_gx[(TT + 1) * GXS + r1];                          \
        __syncthreads();                                                       \
        /* combine: pure 4-way sum (ih+bias already folded into partials) */   \
        float p0 = s_part[BUF][0][crow];                                       \
        float p1 = s_part[BUF][1][crow];                                       \
        float p2 = s_part[BUF][2][crow];                                       \
        float p3 = s_part[BUF][3][crow];                                       \
        float pre = (p0 + p1) + (p2 + p3);                                     \
        if ((wv == 3) && (DO_L1))                                              \
            l1_step(gxn, bias1, w1h, isc1, osc1, off1, st);                    \
        float act2 = fmaf(osc2, fast_sigm(isc2 * pre), off2);                  \
        float v1 = qperm<0xB1>(act2);                                          \
        float v2 = qperm<0x4E>(act2);                                          \
        float v3 = qperm<0x1B>(act2);                                          \
        c2 = fmaf(v1, c2, act2 * v2);                                          \
        float hn = v3 * fast_tanh(c2);                                         \
        if (g == 0 && onc) s_h2[u] = hn;                                       \
        /* refresh wave-uniform h multipliers from my own lanes */             \
        _Pragma("unroll")                                                      \
        for (int k = 0; k < KW; ++k) hsl[k] = rdlane(hn, 4 * k);               \
        if (wv == 3) {                                                         \
            hsl[6]  = st.h0; hsl[7]  = st.h1; hsl[8] = st.h2;                  \
            hsl[9]  = st.h3; hsl[10] = st.h4;                                  \
            hsl[11] = 1.f;                                                     \
        }                                                                      \
    }

    #pragma unroll 1
    for (int c = 0; c < NCHUNK; ++c) {
        // ---- stage x chunk into padded rows (coalesced global read) ----
        {
            float4 v = ((const float4*)(xb + (size_t)c * CHUNK * DIN))[tid];
            const int stp = tid >> 2, col = (tid & 3) * 4;
            float* dst = s_x + stp * XS + col;
            dst[0] = v.x; dst[1] = v.y; dst[2] = v.z; dst[3] = v.w;
        }
        __syncthreads();

        // ---- x-part gates: thread = (step, q); 5 rows each ----
        {
            const int stp = tid >> 2, q = tid & 3;
            const float* xs = s_x + stp * XS;
            float x0 = xs[0],  x1 = xs[1],  x2 = xs[2],  x3 = xs[3];
            float x4 = xs[4],  x5 = xs[5],  x6 = xs[6],  x7 = xs[7];
            float x8 = xs[8],  x9 = xs[9],  xA = xs[10], xB = xs[11];
            float xC = xs[12], xD = xs[13], xE = xs[14], xF = xs[15];
            #pragma unroll
            for (int r = 0; r < 5; ++r) {
                const int rw = q * 5 + r;
                const float* wr = s_w1 + rw * DIN;
                float s = wr[0] * x0;
                s = fmaf(wr[1],  x1, s); s = fmaf(wr[2],  x2, s); s = fmaf(wr[3],  x3, s);
                s = fmaf(wr[4],  x4, s); s = fmaf(wr[5],  x5, s); s = fmaf(wr[6],  x6, s);
                s = fmaf(wr[7],  x7, s); s = fmaf(wr[8],  x8, s); s = fmaf(wr[9],  x9, s);
                s = fmaf(wr[10], xA, s); s = fmaf(wr[11], xB, s); s = fmaf(wr[12], xC, s);
                s = fmaf(wr[13], xD, s); s = fmaf(wr[14], xE, s); s = fmaf(wr[15], xF, s);
                s_gx[stp * GXS + rw] = s;
            }
        }
        __syncthreads();

        // ---- chunk preamble: L1 for this chunk's step 0 (wave 3 only) ----
        if (wv == 3) {
            l1_step(s_gx[r1], bias1, w1h, isc1, osc1, off1, st);
            hsl[6]  = st.h0; hsl[7]  = st.h1; hsl[8] = st.h2;
            hsl[9]  = st.h3; hsl[10] = st.h4;
            hsl[11] = 1.f;
        }

        #pragma unroll 1
        for (int tt = 0; tt < CHUNK; tt += 2) {
            LSTM_STEP(0, tt, true)
            LSTM_STEP(1, tt + 1, (tt < CHUNK - 2))
        }
    }
    #undef LSTM_STEP

    __syncthreads();
    // ---- outputs: result(256,20) @0, last(256,50) @5120 ----
    if (tid < NH2) out[BATCH * NCLS + b * NH2 + tid] = s_h2[tid];
    if (tid < NCLS) {
        float acc = bfc[tid];
        const float* wr = Wfc + tid * NH2;
        #pragma unroll
        for (int j = 0; j < NH2; ++j) acc = fmaf(s_h2[j], wr[j], acc);
        out[b * NCLS + tid] = acc;
    }
}

} // namespace

extern "C" void kernel_launch(void* const* d_in, const int* in_sizes, int n_in,
                              void* d_out, int out_size, void* d_ws, size_t ws_size,
                              hipStream_t stream) {
    (void)in_sizes; (void)n_in; (void)d_ws; (void)ws_size; (void)out_size;
    const float* x    = (const float*)d_in[0];
    const float* W1ih = (const float*)d_in[1];
    const float* W1hh = (const float*)d_in[2];
    const float* b1ih = (const float*)d_in[3];
    const float* b1hh = (const float*)d_in[4];
    const float* W2ih = (const float*)d_in[5];
    const float* W2hh = (const float*)d_in[6];
    const float* b2ih = (const float*)d_in[7];
    const float* b2hh = (const float*)d_in[8];
    const float* Wfc  = (const float*)d_in[9];
    const float* bfc  = (const float*)d_in[10];

    lstm_fused_kernel<<<dim3(BATCH), dim3(256), 0, stream>>>(
        x, W1ih, W1hh, b1ih, b1hh, W2ih, W2hh, b2ih, b2hh, Wfc, bfc,
        (float*)d_out);
}